// Round 3
// baseline (399.057 us; speedup 1.0000x reference)
//
#include <hip/hip_runtime.h>

// SOCNet: per-element tiny MLP -> per-row prefix sum (cumsum) + scalar init.
// One block per batch row; 8 tiles of 1024 elements; block-wide scan per tile.
// Backward-looking formulation: c[s] = rate[s-1]*(t[s]-t[s-1]) so no thread
// ever needs data from a FUTURE element -> next tile is prefetched before the
// scan barriers (latency hides under scan).

#define BLOCK 1024

__device__ __forceinline__ float softplusf(float x) {
    // stable, matches jax.nn.softplus = logaddexp(x, 0)
    return fmaxf(x, 0.0f) + log1pf(expf(-fabsf(x)));
}

__global__ __launch_bounds__(BLOCK) void soc_scan_kernel(
    const float* __restrict__ X,
    const float* __restrict__ SC,
    const float* __restrict__ W1, const float* __restrict__ b1,
    const float* __restrict__ W2, const float* __restrict__ b2,
    const float* __restrict__ Wa, const float* __restrict__ ba,
    const float* __restrict__ Wb, const float* __restrict__ bb,
    float* __restrict__ out, const int S)
{
    const int b    = blockIdx.x;
    const int tid  = threadIdx.x;
    const int lane = tid & 63;
    const int wv   = tid >> 6;
    const int NW   = BLOCK >> 6;   // 16 waves

    __shared__ float sEdgeRate[16];
    __shared__ float sEdgeT[16];
    __shared__ float sWaveSum[16];
    __shared__ float sWaveOff[16];
    __shared__ float sBlockTot;
    __shared__ float sPrevRate;
    __shared__ float sPrevT;

    // broadcast scalar weights (uniform loads)
    const float w10 = W1[0], w11 = W1[1], w12 = W1[2], w13 = W1[3];
    const float B1  = b1[0], w2v = W2[0], B2 = b2[0];
    const float wa0 = Wa[0], wa1 = Wa[1], BA = ba[0];
    const float wbv = Wb[0], BB  = bb[0];

    const float Q    = SC[b*4 + 0];
    const float eta0 = SC[b*4 + 1];
    const float Rr   = SC[b*4 + 2];
    const float sc3  = SC[b*4 + 3];

    const float4* __restrict__ Xrow = (const float4*)X + (size_t)b * S;
    float* __restrict__ orow = out + (size_t)b * S;

    // per-row init scalar: uses element 0's (I,T,U) and SC
    float4 x0 = Xrow[0];
    const float h0   = softplusf(x0.y*w10 + x0.z*w11 + x0.w*w12 + Rr*w13 + B1);
    const float soc0 = sc3 * (1.0f + (h0*w2v + B2));
    const float denom = 3600.0f * Q;

    float4 x = Xrow[tid];          // tile 0 element (coalesced float4)
    float carry = 0.0f;

    for (int tile = 0; tile < S; tile += BLOCK) {
        const int s = tile + tid;

        // prefetch next tile BEFORE the barrier chain (latency hides under scan)
        const int snext = (tile + BLOCK < S) ? (s + BLOCK) : s;
        float4 xn = Xrow[snext];

        const float t  = x.x;
        const float de   = softplusf(x.y*wa0 + x.z*wa1 + BA) * wbv + BB;
        const float rate = eta0 * (1.0f + de) * x.y / denom;

        // expose (rate, t) to successor thread across wave boundaries
        if (lane == 63) { sEdgeRate[wv] = rate; sEdgeT[wv] = t; }
        __syncthreads();

        float rp = __shfl_up(rate, 1, 64);
        float tp = __shfl_up(t,    1, 64);
        if (lane == 0) {
            if (wv > 0) { rp = sEdgeRate[wv - 1]; tp = sEdgeT[wv - 1]; }
            else        { rp = sPrevRate;         tp = sPrevT;         }
        }
        // contribution ENDING at s (c[0] = 0); sPrev* garbage only when s==0,
        // where the ternary selects 0.
        const float c = (s == 0) ? 0.0f : rp * (t - tp);

        // inclusive scan within wave
        float v = c;
        #pragma unroll
        for (int off = 1; off < 64; off <<= 1) {
            float n = __shfl_up(v, off, 64);
            if (lane >= off) v += n;
        }
        if (lane == 63) sWaveSum[wv] = v;
        __syncthreads();

        // scan the 16 wave sums with wave 0
        if (wv == 0 && lane < NW) {
            float ws  = sWaveSum[lane];
            float acc = ws;
            #pragma unroll
            for (int off = 1; off < 16; off <<= 1) {
                float n = __shfl_up(acc, off, 64);
                if (lane >= off) acc += n;
            }
            sWaveOff[lane] = acc - ws;          // exclusive wave offset
            if (lane == NW - 1) sBlockTot = acc;
        }
        __syncthreads();

        orow[s] = soc0 + carry + sWaveOff[wv] + v;   // coalesced store
        carry += sBlockTot;

        if (tid == BLOCK - 1) { sPrevRate = rate; sPrevT = t; } // tile edge
        x = xn;
    }
}

extern "C" void kernel_launch(void* const* d_in, const int* in_sizes, int n_in,
                              void* d_out, int out_size, void* d_ws, size_t ws_size,
                              hipStream_t stream) {
    const float* X  = (const float*)d_in[0];
    const float* SC = (const float*)d_in[1];
    const float* W1 = (const float*)d_in[2];
    const float* b1 = (const float*)d_in[3];
    const float* W2 = (const float*)d_in[4];
    const float* b2 = (const float*)d_in[5];
    const float* Wa = (const float*)d_in[6];
    const float* ba = (const float*)d_in[7];
    const float* Wb = (const float*)d_in[8];
    const float* bb = (const float*)d_in[9];
    float* out = (float*)d_out;

    const int B = in_sizes[1] / 4;              // SC is (B,4)
    const int S = in_sizes[0] / (B * 4);        // X is (B,S,4)

    soc_scan_kernel<<<B, BLOCK, 0, stream>>>(X, SC, W1, b1, W2, b2,
                                             Wa, ba, Wb, bb, out, S);
}

// Round 6
// 395.371 us; speedup vs baseline: 1.0093x; 1.0093x over previous
//
#include <hip/hip_runtime.h>

// SOCNet: per-element tiny MLP -> per-row cumsum + scalar init.
// v2: one block per row, 8 elements/thread (strided, coalesced), ALL loads
// issued up front (128KB/block in flight), single scan hierarchy for the
// whole row: 8 independent wave scans (ILP) -> one 128-wide wave-0 scan ->
// stores. 3 barriers per row (was 24) and no serial inter-tile carry.

#define BLOCK 1024
#define NT 8            // elements per thread; specialized for S = 8192

__device__ __forceinline__ float softplusf(float x) {
    // stable, matches jax.nn.softplus = logaddexp(x, 0)
    return fmaxf(x, 0.0f) + log1pf(expf(-fabsf(x)));
}

__global__ __launch_bounds__(BLOCK) void soc_row_kernel(
    const float* __restrict__ X,
    const float* __restrict__ SC,
    const float* __restrict__ W1, const float* __restrict__ b1,
    const float* __restrict__ W2, const float* __restrict__ b2,
    const float* __restrict__ Wa, const float* __restrict__ ba,
    const float* __restrict__ Wb, const float* __restrict__ bb,
    float* __restrict__ out)
{
    const int b    = blockIdx.x;
    const int tid  = threadIdx.x;
    const int lane = tid & 63;
    const int wv   = tid >> 6;          // 0..15

    __shared__ float sER[NT][16];       // per-(tile,wave) edge rate (lane 63)
    __shared__ float sET[NT][16];       // per-(tile,wave) edge time
    __shared__ float sWS[NT * 16];      // per-(tile,wave) inclusive wave sums
    __shared__ float sOff[NT * 16];     // exclusive offsets for each (tile,wave)

    const float w10 = W1[0], w11 = W1[1], w12 = W1[2], w13 = W1[3];
    const float B1  = b1[0], w2v = W2[0], B2 = b2[0];
    const float wa0 = Wa[0], wa1 = Wa[1], BA = ba[0];
    const float wbv = Wb[0], BB  = bb[0];

    const float Q    = SC[b*4 + 0];
    const float eta0 = SC[b*4 + 1];
    const float Rr   = SC[b*4 + 2];
    const float sc3  = SC[b*4 + 3];
    const float denom = 3600.0f * Q;

    const float4* __restrict__ Xrow = (const float4*)X + (size_t)b * (NT * BLOCK);
    float* __restrict__ orow = out + (size_t)b * (NT * BLOCK);

    // per-row init scalar (element 0; broadcast load, cache-served)
    float4 x0 = Xrow[0];
    const float h0   = softplusf(x0.y*w10 + x0.z*w11 + x0.w*w12 + Rr*w13 + B1);
    const float soc0 = sc3 * (1.0f + (h0*w2v + B2));

    // ---- phase 1: issue ALL loads (coalesced float4, 8 independent) ----
    float4 x[NT];
    #pragma unroll
    for (int j = 0; j < NT; ++j) x[j] = Xrow[j * BLOCK + tid];

    // ---- phase 2: pointwise MLP -> (rate, t); publish wave-edge values ----
    float rate[NT], tv[NT];
    #pragma unroll
    for (int j = 0; j < NT; ++j) {
        tv[j] = x[j].x;
        const float de = softplusf(x[j].y*wa0 + x[j].z*wa1 + BA) * wbv + BB;
        rate[j] = eta0 * (1.0f + de) * x[j].y / denom;
        if (lane == 63) { sER[j][wv] = rate[j]; sET[j][wv] = tv[j]; }
    }
    __syncthreads();

    // ---- phase 3: 8 independent wave scans of c[s]=rate[s-1]*(t[s]-t[s-1]) ----
    float v[NT];
    #pragma unroll
    for (int j = 0; j < NT; ++j) {
        float rp = __shfl_up(rate[j], 1, 64);
        float tp = __shfl_up(tv[j],   1, 64);
        if (lane == 0) {
            if (wv > 0)     { rp = sER[j][wv-1]; tp = sET[j][wv-1]; }
            else if (j > 0) { rp = sER[j-1][15]; tp = sET[j-1][15]; }
            // j==0 && tid==0: shfl_up returns own value -> tv-tp == 0 -> c == 0
        }
        float c = rp * (tv[j] - tp);
        v[j] = c;
        #pragma unroll
        for (int off = 1; off < 64; off <<= 1) {
            float n = __shfl_up(v[j], off, 64);
            if (lane >= off) v[j] += n;
        }
        if (lane == 63) sWS[j * 16 + wv] = v[j];
    }
    __syncthreads();

    // ---- phase 4: wave 0 scans all 128 (tile,wave) sums; order = j*16+wv ----
    if (wv == 0) {
        const float2 p2 = ((const float2*)sWS)[lane];
        const float p   = p2.x + p2.y;
        float acc = p;
        #pragma unroll
        for (int off = 1; off < 64; off <<= 1) {
            float n = __shfl_up(acc, off, 64);
            if (lane >= off) acc += n;
        }
        const float excl = acc - p;
        sOff[2*lane]     = excl;
        sOff[2*lane + 1] = excl + p2.x;
    }
    __syncthreads();

    // ---- phase 5: coalesced stores ----
    #pragma unroll
    for (int j = 0; j < NT; ++j)
        orow[j * BLOCK + tid] = soc0 + sOff[j * 16 + wv] + v[j];
}

// ---------- generic fallback (previous passing kernel) for S != NT*BLOCK ----
__global__ __launch_bounds__(BLOCK) void soc_scan_generic(
    const float* __restrict__ X, const float* __restrict__ SC,
    const float* __restrict__ W1, const float* __restrict__ b1,
    const float* __restrict__ W2, const float* __restrict__ b2,
    const float* __restrict__ Wa, const float* __restrict__ ba,
    const float* __restrict__ Wb, const float* __restrict__ bb,
    float* __restrict__ out, const int S)
{
    const int b    = blockIdx.x;
    const int tid  = threadIdx.x;
    const int lane = tid & 63;
    const int wv   = tid >> 6;
    const int NW   = BLOCK >> 6;

    __shared__ float sEdgeRate[16], sEdgeT[16], sWaveSum[16], sWaveOff[16];
    __shared__ float sBlockTot, sPrevRate, sPrevT;

    const float w10 = W1[0], w11 = W1[1], w12 = W1[2], w13 = W1[3];
    const float B1  = b1[0], w2v = W2[0], B2 = b2[0];
    const float wa0 = Wa[0], wa1 = Wa[1], BA = ba[0];
    const float wbv = Wb[0], BB  = bb[0];

    const float Q    = SC[b*4 + 0];
    const float eta0 = SC[b*4 + 1];
    const float Rr   = SC[b*4 + 2];
    const float sc3  = SC[b*4 + 3];

    const float4* __restrict__ Xrow = (const float4*)X + (size_t)b * S;
    float* __restrict__ orow = out + (size_t)b * S;

    float4 x0 = Xrow[0];
    const float h0   = softplusf(x0.y*w10 + x0.z*w11 + x0.w*w12 + Rr*w13 + B1);
    const float soc0 = sc3 * (1.0f + (h0*w2v + B2));
    const float denom = 3600.0f * Q;

    float4 x = Xrow[tid];
    float carry = 0.0f;

    for (int tile = 0; tile < S; tile += BLOCK) {
        const int s = tile + tid;
        const int snext = (tile + BLOCK < S) ? (s + BLOCK) : s;
        float4 xn = Xrow[snext];

        const float t    = x.x;
        const float de   = softplusf(x.y*wa0 + x.z*wa1 + BA) * wbv + BB;
        const float rate = eta0 * (1.0f + de) * x.y / denom;

        if (lane == 63) { sEdgeRate[wv] = rate; sEdgeT[wv] = t; }
        __syncthreads();

        float rp = __shfl_up(rate, 1, 64);
        float tp = __shfl_up(t,    1, 64);
        if (lane == 0) {
            if (wv > 0) { rp = sEdgeRate[wv - 1]; tp = sEdgeT[wv - 1]; }
            else        { rp = sPrevRate;         tp = sPrevT;         }
        }
        const float c = (s == 0) ? 0.0f : rp * (t - tp);

        float v = c;
        #pragma unroll
        for (int off = 1; off < 64; off <<= 1) {
            float n = __shfl_up(v, off, 64);
            if (lane >= off) v += n;
        }
        if (lane == 63) sWaveSum[wv] = v;
        __syncthreads();

        if (wv == 0 && lane < NW) {
            float ws  = sWaveSum[lane];
            float acc = ws;
            #pragma unroll
            for (int off = 1; off < 16; off <<= 1) {
                float n = __shfl_up(acc, off, 64);
                if (lane >= off) acc += n;
            }
            sWaveOff[lane] = acc - ws;
            if (lane == NW - 1) sBlockTot = acc;
        }
        __syncthreads();

        orow[s] = soc0 + carry + sWaveOff[wv] + v;
        carry += sBlockTot;

        if (tid == BLOCK - 1) { sPrevRate = rate; sPrevT = t; }
        x = xn;
    }
}

extern "C" void kernel_launch(void* const* d_in, const int* in_sizes, int n_in,
                              void* d_out, int out_size, void* d_ws, size_t ws_size,
                              hipStream_t stream) {
    const float* X  = (const float*)d_in[0];
    const float* SC = (const float*)d_in[1];
    const float* W1 = (const float*)d_in[2];
    const float* b1 = (const float*)d_in[3];
    const float* W2 = (const float*)d_in[4];
    const float* b2 = (const float*)d_in[5];
    const float* Wa = (const float*)d_in[6];
    const float* ba = (const float*)d_in[7];
    const float* Wb = (const float*)d_in[8];
    const float* bb = (const float*)d_in[9];
    float* out = (float*)d_out;

    const int B = in_sizes[1] / 4;              // SC is (B,4)
    const int S = in_sizes[0] / (B * 4);        // X is (B,S,4)

    if (S == NT * BLOCK) {
        soc_row_kernel<<<B, BLOCK, 0, stream>>>(X, SC, W1, b1, W2, b2,
                                                Wa, ba, Wb, bb, out);
    } else {
        soc_scan_generic<<<B, BLOCK, 0, stream>>>(X, SC, W1, b1, W2, b2,
                                                  Wa, ba, Wb, bb, out, S);
    }
}